// Round 19
// baseline (249.343 us; speedup 1.0000x reference)
//
#include <hip/hip_runtime.h>

#define BB 4
#define NN 512
#define FF 64

typedef __attribute__((ext_vector_type(8))) _Float16 half8v;   // 8 f16 = 4 VGPR
typedef __attribute__((ext_vector_type(4))) float f32x4;

__device__ __forceinline__ float silu_f(float v) {
  return v * __builtin_amdgcn_rcpf(1.0f + __expf(-v));
}
__device__ __forceinline__ unsigned cvt_pk_f16(float a, float b) {
  auto r = __builtin_amdgcn_cvt_pkrtz(a, b);   // __fp16 ext_vector(2)
  unsigned u; __builtin_memcpy(&u, &r, 4); return u;
}
__device__ __forceinline__ unsigned short f2h(float w) {
  _Float16 hf = (_Float16)w;          // RNE
  unsigned short us; __builtin_memcpy(&us, &hf, 2); return us;
}
__device__ __forceinline__ half8v mk_half8(unsigned u0, unsigned u1, unsigned u2, unsigned u3) {
  uint4 uu = make_uint4(u0, u1, u2, u3);
  half8v r; __builtin_memcpy(&r, &uu, 16); return r;
}

// act LDS addressing within a 16-row wave region: [j 0..15][k 0..63] f16,
// 16B slots XOR-swizzled by j (rows are 128B = all 32 banks).
#define AIDX(j, k) ((((j) << 6)) | (((((k) >> 3) ^ ((j) & 7))) << 3) | ((k) & 7))

// ---------------- prep kernel (unchanged) ----------------
__global__ void sake_prep(const float* __restrict__ h, const float* __restrict__ We1,
                          const float* __restrict__ be1, const float* __restrict__ We2,
                          const float* __restrict__ Wc1, const float* __restrict__ Wc2,
                          float* __restrict__ G, float* __restrict__ Base,
                          unsigned short* __restrict__ w2f,
                          unsigned short* __restrict__ w3f,
                          unsigned short* __restrict__ w4f)
{
  const int wg = (int)blockIdx.x, tid = (int)threadIdx.x;
  if (wg < 64) {
    __shared__ float sH[32][64];
    const int r0 = wg * 32;
    for (int idx = tid; idx < 2048; idx += 256) sH[idx >> 6][idx & 63] = h[r0 * 64 + idx];
    __syncthreads();
    const int rl = tid >> 3;
    const int o0 = (tid & 7) * 8;
    float aG[8], aB[8];
    #pragma unroll
    for (int o = 0; o < 8; ++o) { aG[o] = 0.f; aB[o] = be1[o0 + o]; }
    for (int k = 0; k < 64; ++k) {
      const float hv = sH[rl][k];
      const float4 g0 = *(const float4*)&We1[k * 64 + o0];
      const float4 g1 = *(const float4*)&We1[k * 64 + o0 + 4];
      const float4 b0 = *(const float4*)&We1[(64 + k) * 64 + o0];
      const float4 b1 = *(const float4*)&We1[(64 + k) * 64 + o0 + 4];
      aG[0] = fmaf(hv, g0.x, aG[0]); aG[1] = fmaf(hv, g0.y, aG[1]);
      aG[2] = fmaf(hv, g0.z, aG[2]); aG[3] = fmaf(hv, g0.w, aG[3]);
      aG[4] = fmaf(hv, g1.x, aG[4]); aG[5] = fmaf(hv, g1.y, aG[5]);
      aG[6] = fmaf(hv, g1.z, aG[6]); aG[7] = fmaf(hv, g1.w, aG[7]);
      aB[0] = fmaf(hv, b0.x, aB[0]); aB[1] = fmaf(hv, b0.y, aB[1]);
      aB[2] = fmaf(hv, b0.z, aB[2]); aB[3] = fmaf(hv, b0.w, aB[3]);
      aB[4] = fmaf(hv, b1.x, aB[4]); aB[5] = fmaf(hv, b1.y, aB[5]);
      aB[6] = fmaf(hv, b1.z, aB[6]); aB[7] = fmaf(hv, b1.w, aB[7]);
    }
    const size_t base = (size_t)(r0 + rl) * 64 + o0;
    *(float4*)&G[base]        = make_float4(aG[0], aG[1], aG[2], aG[3]);
    *(float4*)&G[base + 4]    = make_float4(aG[4], aG[5], aG[6], aG[7]);
    *(float4*)&Base[base]     = make_float4(aB[0], aB[1], aB[2], aB[3]);
    *(float4*)&Base[base + 4] = make_float4(aB[4], aB[5], aB[6], aB[7]);
  } else {
    for (int idx = tid; idx < 10240; idx += 256) {
      float w; unsigned short* pf; int pos;
      if (idx < 4096)      { const int o = idx >> 6,          k = idx & 63;
                             w = We2[k * 64 + o]; pf = w2f; pos = o * 64 + k; }
      else if (idx < 8192) { const int t = idx - 4096, o = t >> 6, k = t & 63;
                             w = Wc1[k * 64 + o]; pf = w3f; pos = o * 64 + k; }
      else                 { const int t = idx - 8192, c = t >> 6, k = t & 63;
                             w = Wc2[k * 32 + c]; pf = w4f; pos = c * 64 + k; }
      pf[pos] = f2h(w);
    }
  }
}

// ---------------- main kernel ----------------
// R19: BARRIER-FREE main loop. One WAVE per (b,i) row (4 rows per 256-thr
// block); j in tiles of 16 (j = l15). The L1 output is computed directly into
// the lane's MFMA B-frag registers; L2->C1 and C1->C2 transposes go through
// 2KB wave-PRIVATE LDS regions (same-wave ordering via compiler lgkmcnt, no
// __syncthreads). Weights/biases re-read from block-shared LDS each iter.
// 12 waves/CU now interleave with NO convergence points.
// (256,3): the only non-spilling config (session law, 5 confirmations).
__global__ __launch_bounds__(256, 3)
void sake_wave(const float* __restrict__ h, const float* __restrict__ x,
               const float* __restrict__ mask,
               const float* __restrict__ We1, const float* __restrict__ be2,
               const float* __restrict__ bc1, const float* __restrict__ bc2,
               const float* __restrict__ Wp1, const float* __restrict__ bp1,
               const float* __restrict__ Wp2, const float* __restrict__ bp2,
               const float* __restrict__ Wn1, const float* __restrict__ bn1,
               const float* __restrict__ Wn2, const float* __restrict__ bn2,
               const float* __restrict__ G, const float* __restrict__ Base,
               const unsigned short* __restrict__ w2f,
               const unsigned short* __restrict__ w3f,
               const unsigned short* __restrict__ w4f,
               float* __restrict__ out)
{
  __shared__ unsigned short sW2[4096], sW3[4096], sW4[2048];   // [feat][k] f16
  __shared__ float sB2[64], sB3[64], sB4[32], sW1n[64];
  __shared__ float sBaseW[4][64], sHiW[4][64];
  __shared__ unsigned short sActA[4][1024], sActB[4][1024];    // wave-private
  __shared__ float sHeW[4][64], sCombW[4][96], sCNW[4][32];
  __shared__ float sTmpW[4][64], sHcombW[4][64];

  const int tid  = (int)threadIdx.x;
  const int blk  = (int)blockIdx.x;          // 0..511
  const int wid  = tid >> 6;                 // wave 0..3
  const int lane = tid & 63;
  const int l15  = lane & 15;                // j within tile
  const int lg   = lane >> 4;                // 0..3 (k-chunk / feat sub)
  const int row  = blk * 4 + wid;            // global (b,i) row
  const int b    = row >> 9;
  const int i    = row & 511;

  const size_t mrow = ((size_t)row) * NN;

  // ---- block-shared staging ----
  for (int idx = tid; idx < 2048; idx += 256) ((uint*)sW2)[idx] = ((const uint*)w2f)[idx];
  for (int idx = tid; idx < 2048; idx += 256) ((uint*)sW3)[idx] = ((const uint*)w3f)[idx];
  for (int idx = tid; idx < 1024; idx += 256) ((uint*)sW4)[idx] = ((const uint*)w4f)[idx];
  if (tid < 64) { sB2[tid] = be2[tid]; sB3[tid] = bc1[tid]; sW1n[tid] = We1[128 * 64 + tid]; }
  if (tid >= 64 && tid < 96) sB4[tid - 64] = bc2[tid - 64];
  // per-wave staging
  sBaseW[wid][lane] = Base[((size_t)row) * 64 + lane];
  sHiW[wid][lane]   = h[((size_t)row) * 64 + lane];
  const float xi0 = x[((size_t)row) * 3 + 0];
  const float xi1 = x[((size_t)row) * 3 + 1];
  const float xi2 = x[((size_t)row) * 3 + 2];
  __syncthreads();   // the ONLY block barrier

  float heAcc[4][4] = {};
  float cAcc[2][4][3] = {};

  for (int jt = 0; jt < 32; ++jt) {
    const int j = jt * 16 + l15;             // this lane's j for the whole iter
    const size_t xo = ((size_t)(b * NN + j)) * 3;
    const float dx = x[xo + 0] - xi0;
    const float dy = x[xo + 1] - xi1;
    const float dz = x[xo + 2] - xi2;
    const float n2 = dx * dx + dy * dy + dz * dz;
    const float inv = __builtin_amdgcn_rcpf(n2 * n2 + 1e-10f);
    const float m = mask[mrow + j];
    const float vm0 = dx * inv * m, vm1 = dy * inv * m, vm2 = dz * inv * m;

    // ---- L1 directly into B-frag registers ----
    half8v a1[2];
    #pragma unroll
    for (int ks = 0; ks < 2; ++ks) {
      const int kb = ks * 32 + lg * 8;
      const float4 g0 = *(const float4*)&G[((size_t)(b * NN + j)) * 64 + kb];
      const float4 g1 = *(const float4*)&G[((size_t)(b * NN + j)) * 64 + kb + 4];
      const f32x4 bs0 = *(const f32x4*)&sBaseW[wid][kb];
      const f32x4 bs1 = *(const f32x4*)&sBaseW[wid][kb + 4];
      const f32x4 wn0 = *(const f32x4*)&sW1n[kb];
      const f32x4 wn1 = *(const f32x4*)&sW1n[kb + 4];
      const float v0 = silu_f(g0.x + bs0[0] + n2 * wn0[0]);
      const float v1 = silu_f(g0.y + bs0[1] + n2 * wn0[1]);
      const float v2 = silu_f(g0.z + bs0[2] + n2 * wn0[2]);
      const float v3 = silu_f(g0.w + bs0[3] + n2 * wn0[3]);
      const float v4 = silu_f(g1.x + bs1[0] + n2 * wn1[0]);
      const float v5 = silu_f(g1.y + bs1[1] + n2 * wn1[1]);
      const float v6 = silu_f(g1.z + bs1[2] + n2 * wn1[2]);
      const float v7 = silu_f(g1.w + bs1[3] + n2 * wn1[3]);
      a1[ks] = mk_half8(cvt_pk_f16(v0, v1), cvt_pk_f16(v2, v3),
                        cvt_pk_f16(v4, v5), cvt_pk_f16(v6, v7));
    }

    // ---- L2: act2 = silu(act1 @ We2 + be2) ; h_e accum ; -> sActA[wid] ----
    #pragma unroll
    for (int fb = 0; fb < 4; ++fb) {
      f32x4 acc = *(const f32x4*)&sB2[fb * 16 + lg * 4];
      #pragma unroll
      for (int ks = 0; ks < 2; ++ks) {
        const half8v wA = *(const half8v*)&sW2[(fb * 16 + l15) * 64 + ks * 32 + lg * 8];
        acc = __builtin_amdgcn_mfma_f32_16x16x32_f16(wA, a1[ks], acc, 0, 0, 0);
      }
      float v[4];
      #pragma unroll
      for (int r = 0; r < 4; ++r) { v[r] = silu_f(acc[r]); heAcc[fb][r] = fmaf(v[r], m, heAcc[fb][r]); }
      *(uint2*)&sActA[wid][AIDX(l15, fb * 16 + lg * 4)] =
          make_uint2(cvt_pk_f16(v[0], v[1]), cvt_pk_f16(v[2], v[3]));
    }
    half8v a2[2];
    a2[0] = *(const half8v*)&sActA[wid][AIDX(l15, lg * 8)];
    a2[1] = *(const half8v*)&sActA[wid][AIDX(l15, 32 + lg * 8)];

    // ---- C1: act3 = silu(act2 @ Wc1 + bc1) -> sActB[wid] ----
    #pragma unroll
    for (int fb = 0; fb < 4; ++fb) {
      f32x4 acc = *(const f32x4*)&sB3[fb * 16 + lg * 4];
      #pragma unroll
      for (int ks = 0; ks < 2; ++ks) {
        const half8v wA = *(const half8v*)&sW3[(fb * 16 + l15) * 64 + ks * 32 + lg * 8];
        acc = __builtin_amdgcn_mfma_f32_16x16x32_f16(wA, a2[ks], acc, 0, 0, 0);
      }
      float v[4];
      #pragma unroll
      for (int r = 0; r < 4; ++r) v[r] = silu_f(acc[r]);
      *(uint2*)&sActB[wid][AIDX(l15, fb * 16 + lg * 4)] =
          make_uint2(cvt_pk_f16(v[0], v[1]), cvt_pk_f16(v[2], v[3]));
    }
    half8v a3[2];
    a3[0] = *(const half8v*)&sActB[wid][AIDX(l15, lg * 8)];
    a3[1] = *(const half8v*)&sActB[wid][AIDX(l15, 32 + lg * 8)];

    // ---- C2: coeff = act3 @ Wc2 + bc2 ; comb accum ----
    #pragma unroll
    for (int cb = 0; cb < 2; ++cb) {
      f32x4 acc = *(const f32x4*)&sB4[cb * 16 + lg * 4];
      #pragma unroll
      for (int ks = 0; ks < 2; ++ks) {
        const half8v wA = *(const half8v*)&sW4[(cb * 16 + l15) * 64 + ks * 32 + lg * 8];
        acc = __builtin_amdgcn_mfma_f32_16x16x32_f16(wA, a3[ks], acc, 0, 0, 0);
      }
      #pragma unroll
      for (int r = 0; r < 4; ++r) {
        cAcc[cb][r][0] = fmaf(acc[r], vm0, cAcc[cb][r][0]);
        cAcc[cb][r][1] = fmaf(acc[r], vm1, cAcc[cb][r][1]);
        cAcc[cb][r][2] = fmaf(acc[r], vm2, cAcc[cb][r][2]);
      }
    }
  }

  // -------- per-wave reductions (reduce over l15 = j) --------
  #pragma unroll
  for (int fb = 0; fb < 4; ++fb)
    #pragma unroll
    for (int r = 0; r < 4; ++r) {
      float s = heAcc[fb][r];
      s += __shfl_xor(s, 1); s += __shfl_xor(s, 2); s += __shfl_xor(s, 4); s += __shfl_xor(s, 8);
      if (l15 == 0) sHeW[wid][fb * 16 + lg * 4 + r] = s;
    }
  #pragma unroll
  for (int cb = 0; cb < 2; ++cb)
    #pragma unroll
    for (int r = 0; r < 4; ++r)
      #pragma unroll
      for (int d = 0; d < 3; ++d) {
        float s = cAcc[cb][r][d];
        s += __shfl_xor(s, 1); s += __shfl_xor(s, 2); s += __shfl_xor(s, 4); s += __shfl_xor(s, 8);
        if (l15 == 0) sCombW[wid][(cb * 16 + lg * 4 + r) * 3 + d] = s;
      }
  // comb_norm (wave-internal; compiler orders LDS via lgkmcnt)
  if (lane < 32) {
    const int c = lane;
    const float s0 = sCombW[wid][c * 3 + 0];
    const float s1 = sCombW[wid][c * 3 + 1];
    const float s2 = sCombW[wid][c * 3 + 2];
    sCNW[wid][c] = s0 * s0 + s1 * s1 + s2 * s2;
  }
  // -------- per-wave epilogue MLPs (fp32, no barriers) --------
  {
    float s = bp1[lane];
    #pragma unroll 8
    for (int c = 0; c < 32; ++c) s = fmaf(sCNW[wid][c], Wp1[c * 64 + lane], s);
    sTmpW[wid][lane] = silu_f(s);
  }
  {
    float s = bp2[lane];
    #pragma unroll 16
    for (int k = 0; k < 64; ++k) s = fmaf(sTmpW[wid][k], Wp2[k * 64 + lane], s);
    sHcombW[wid][lane] = s;
  }
  {
    float s = bn1[lane];
    #pragma unroll 16
    for (int mm = 0; mm < 64; ++mm) s = fmaf(sHiW[wid][mm],    Wn1[mm * 64 + lane],         s);
    #pragma unroll 16
    for (int mm = 0; mm < 64; ++mm) s = fmaf(sHeW[wid][mm],    Wn1[(64 + mm) * 64 + lane],  s);
    #pragma unroll 16
    for (int mm = 0; mm < 64; ++mm) s = fmaf(sHcombW[wid][mm], Wn1[(128 + mm) * 64 + lane], s);
    sTmpW[wid][lane] = silu_f(s);
  }
  {
    float s = bn2[lane];
    #pragma unroll 16
    for (int k = 0; k < 64; ++k) s = fmaf(sTmpW[wid][k], Wn2[k * 64 + lane], s);
    out[((size_t)row) * 64 + lane] = sHiW[wid][lane] + s;
  }
  if (lane < 3) {
    out[(size_t)BB * NN * FF + ((size_t)row) * 3 + lane] = x[((size_t)row) * 3 + lane];
  }
}

extern "C" void kernel_launch(void* const* d_in, const int* in_sizes, int n_in,
                              void* d_out, int out_size, void* d_ws, size_t ws_size,
                              hipStream_t stream) {
  const float* h    = (const float*)d_in[0];
  const float* x    = (const float*)d_in[1];
  const float* mask = (const float*)d_in[2];
  const float* We1  = (const float*)d_in[3];
  const float* be1  = (const float*)d_in[4];
  const float* We2  = (const float*)d_in[5];
  const float* be2  = (const float*)d_in[6];
  const float* Wc1  = (const float*)d_in[7];
  const float* bc1  = (const float*)d_in[8];
  const float* Wc2  = (const float*)d_in[9];
  const float* bc2  = (const float*)d_in[10];
  const float* Wp1  = (const float*)d_in[11];
  const float* bp1  = (const float*)d_in[12];
  const float* Wp2  = (const float*)d_in[13];
  const float* bp2  = (const float*)d_in[14];
  const float* Wn1  = (const float*)d_in[15];
  const float* bn1  = (const float*)d_in[16];
  const float* Wn2  = (const float*)d_in[17];
  const float* bn2  = (const float*)d_in[18];
  float* out = (float*)d_out;

  float* G    = (float*)d_ws;                       // 2048*64 f32
  float* Base = G + 2048 * 64;                      // 2048*64 f32
  unsigned short* w2f = (unsigned short*)(Base + 2048 * 64);
  unsigned short* w3f = w2f + 4096;
  unsigned short* w4f = w3f + 4096;

  hipLaunchKernelGGL(sake_prep, dim3(65), dim3(256), 0, stream,
                     h, We1, be1, We2, Wc1, Wc2, G, Base, w2f, w3f, w4f);
  hipLaunchKernelGGL(sake_wave, dim3(BB * NN / 4), dim3(256), 0, stream,
                     h, x, mask, We1, be2, bc1, bc2,
                     Wp1, bp1, Wp2, bp2, Wn1, bn1, Wn2, bn2,
                     G, Base, w2f, w3f, w4f, out);
}

// Round 20
// 107.535 us; speedup vs baseline: 2.3187x; 2.3187x over previous
//
#include <hip/hip_runtime.h>

#define BB 4
#define NN 512
#define FF 64

typedef __attribute__((ext_vector_type(8))) _Float16 half8v;   // 8 f16 = 4 VGPR
typedef __attribute__((ext_vector_type(4))) float f32x4;

__device__ __forceinline__ float silu_f(float v) {
  return v * __builtin_amdgcn_rcpf(1.0f + __expf(-v));
}
// packed f32x2 -> f16x2 (RTZ), low16 = a
__device__ __forceinline__ unsigned cvt_pk_f16(float a, float b) {
  auto r = __builtin_amdgcn_cvt_pkrtz(a, b);   // __fp16 ext_vector(2)
  unsigned u; __builtin_memcpy(&u, &r, 4); return u;
}
__device__ __forceinline__ unsigned short f2h(float w) {
  _Float16 hf = (_Float16)w;          // RNE
  unsigned short us; __builtin_memcpy(&us, &hf, 2); return us;
}

// act LDS addressing: [j][k] f16 rows of 128B, 16B slots XOR-swizzled by j. j in 0..127.
#define AIDX(j, k) ((((j) << 6)) | (((((k) >> 3) ^ ((j) & 7))) << 3) | ((k) & 7))

// ---------------- prep kernel ----------------
// wg 0..63: G[b,j,o] = h_j @ We1[0:64];  Base[b,i,o] = be1 + h_i @ We1[64:128]
// wg 64   : transpose weights -> fp16 [out][in]
__global__ void sake_prep(const float* __restrict__ h, const float* __restrict__ We1,
                          const float* __restrict__ be1, const float* __restrict__ We2,
                          const float* __restrict__ Wc1, const float* __restrict__ Wc2,
                          float* __restrict__ G, float* __restrict__ Base,
                          unsigned short* __restrict__ w2f,
                          unsigned short* __restrict__ w3f,
                          unsigned short* __restrict__ w4f)
{
  const int wg = (int)blockIdx.x, tid = (int)threadIdx.x;
  if (wg < 64) {
    __shared__ float sH[32][64];
    const int r0 = wg * 32;
    for (int idx = tid; idx < 2048; idx += 256) sH[idx >> 6][idx & 63] = h[r0 * 64 + idx];
    __syncthreads();
    const int rl = tid >> 3;
    const int o0 = (tid & 7) * 8;
    float aG[8], aB[8];
    #pragma unroll
    for (int o = 0; o < 8; ++o) { aG[o] = 0.f; aB[o] = be1[o0 + o]; }
    for (int k = 0; k < 64; ++k) {
      const float hv = sH[rl][k];
      const float4 g0 = *(const float4*)&We1[k * 64 + o0];
      const float4 g1 = *(const float4*)&We1[k * 64 + o0 + 4];
      const float4 b0 = *(const float4*)&We1[(64 + k) * 64 + o0];
      const float4 b1 = *(const float4*)&We1[(64 + k) * 64 + o0 + 4];
      aG[0] = fmaf(hv, g0.x, aG[0]); aG[1] = fmaf(hv, g0.y, aG[1]);
      aG[2] = fmaf(hv, g0.z, aG[2]); aG[3] = fmaf(hv, g0.w, aG[3]);
      aG[4] = fmaf(hv, g1.x, aG[4]); aG[5] = fmaf(hv, g1.y, aG[5]);
      aG[6] = fmaf(hv, g1.z, aG[6]); aG[7] = fmaf(hv, g1.w, aG[7]);
      aB[0] = fmaf(hv, b0.x, aB[0]); aB[1] = fmaf(hv, b0.y, aB[1]);
      aB[2] = fmaf(hv, b0.z, aB[2]); aB[3] = fmaf(hv, b0.w, aB[3]);
      aB[4] = fmaf(hv, b1.x, aB[4]); aB[5] = fmaf(hv, b1.y, aB[5]);
      aB[6] = fmaf(hv, b1.z, aB[6]); aB[7] = fmaf(hv, b1.w, aB[7]);
    }
    const size_t base = (size_t)(r0 + rl) * 64 + o0;
    *(float4*)&G[base]        = make_float4(aG[0], aG[1], aG[2], aG[3]);
    *(float4*)&G[base + 4]    = make_float4(aG[4], aG[5], aG[6], aG[7]);
    *(float4*)&Base[base]     = make_float4(aB[0], aB[1], aB[2], aB[3]);
    *(float4*)&Base[base + 4] = make_float4(aB[4], aB[5], aB[6], aB[7]);
  } else {
    for (int idx = tid; idx < 10240; idx += 256) {
      float w; unsigned short* pf; int pos;
      if (idx < 4096)      { const int o = idx >> 6,          k = idx & 63;
                             w = We2[k * 64 + o]; pf = w2f; pos = o * 64 + k; }
      else if (idx < 8192) { const int t = idx - 4096, o = t >> 6, k = t & 63;
                             w = Wc1[k * 64 + o]; pf = w3f; pos = o * 64 + k; }
      else                 { const int t = idx - 8192, c = t >> 6, k = t & 63;
                             w = Wc2[k * 32 + c]; pf = w4f; pos = c * 64 + k; }
      pf[pos] = f2h(w);
    }
  }
}

__device__ __forceinline__ void pack_store4(unsigned short* sA, int a,
                                            float v0, float v1, float v2, float v3) {
  *(uint2*)&sA[a] = make_uint2(cvt_pk_f16(v0, v1), cvt_pk_f16(v2, v3));
}

// ---------------- main kernel ----------------
// FINAL CONFIG (R14, measured 107.6/107.7us twice; absmax 5.24e5, 4.7x margin).
// TILE=128 (4 tiles), 2-buffer ping-pong, 4 barriers/tile, LDS 36.4KB,
// fp16 MFMA (mfma_f32_16x16x32_f16), single-term weights, (256,3)->84 VGPR.
// SESSION LAWS (do not revisit):
//  - (256,3) is the ONLY non-spilling launch config. (256,4), (256,6),
//    waves_per_eu(4,4), amdgpu_num_vgpr(128), no-declaration, (512,2)+fusion:
//    all spill or lose residency (R4/R6/R10/R12/R15/R16/R18).
//  - Barrier count is second-order: 32/16/12 barriers all ~125us pre-fp16 (R8/R9/R11).
//  - Wave-private barrier-free loses block-level operand reuse: 249us (R19).
__global__ __launch_bounds__(256, 3)
void sake_mfma(const float* __restrict__ h, const float* __restrict__ x,
               const float* __restrict__ mask,
               const float* __restrict__ We1, const float* __restrict__ be2,
               const float* __restrict__ bc1, const float* __restrict__ bc2,
               const float* __restrict__ Wp1, const float* __restrict__ bp1,
               const float* __restrict__ Wp2, const float* __restrict__ bp2,
               const float* __restrict__ Wn1, const float* __restrict__ bn1,
               const float* __restrict__ Wn2, const float* __restrict__ bn2,
               const float* __restrict__ G, const float* __restrict__ Base,
               const unsigned short* __restrict__ w2f,
               const unsigned short* __restrict__ w3f,
               const unsigned short* __restrict__ w4f,
               float* __restrict__ out)
{
  __shared__ unsigned short sAct[2 * 8192];  // bufA | bufB, [j 0..127][k 0..63] swizzled, f16
  __shared__ float sMaskL[128];
  __shared__ float sBase[64], sW1n[64], sHi[64];
  __shared__ float sB2[64], sB3[64], sB4[32];
  __shared__ float sHe[64], sCombP[4][48], sCN[32], sTmp[64], sHcomb[64];

  const int tid  = (int)threadIdx.x;
  const int blk  = (int)blockIdx.x;
  const int b    = blk >> 9;
  const int i    = blk & 511;
  const int lane = tid & 63;
  const int wid  = tid >> 6;
  const int l15  = lane & 15;
  const int lg   = lane >> 4;            // 0..3
  const int mb   = wid * 16;             // feat block (L2/C1)
  const int m2   = wid & 1;              // c-block (C2)
  const int jh   = (wid >> 1) * 16;      // C2 j sub-block

  const size_t mrow = ((size_t)(b * NN + i)) * NN;

  if (tid < 64) {
    sBase[tid] = Base[((size_t)(b * NN + i)) * 64 + tid];
    sW1n[tid]  = We1[128 * 64 + tid];
    sHi[tid]   = h[((size_t)(b * NN + i)) * 64 + tid];
    sB2[tid]   = be2[tid];
    sB3[tid]   = bc1[tid];
  }
  if (tid < 32) sB4[tid] = bc2[tid];
  const float xi0 = x[((size_t)(b * NN + i)) * 3 + 0];
  const float xi1 = x[((size_t)(b * NN + i)) * 3 + 1];
  const float xi2 = x[((size_t)(b * NN + i)) * 3 + 2];

  // weight A-frags in registers (fp16, single term): 24 VGPR total
  half8v w2F[2], w3F[2], w4F[2];
  #pragma unroll
  for (int ks = 0; ks < 2; ++ks) {
    const int ko = ks * 32 + lg * 8;
    w2F[ks] = *(const half8v*)&w2f[(mb + l15) * 64 + ko];
    w3F[ks] = *(const half8v*)&w3f[(mb + l15) * 64 + ko];
    w4F[ks] = *(const half8v*)&w4f[(m2 * 16 + l15) * 64 + ko];
  }

  float heAcc[4] = {0.f, 0.f, 0.f, 0.f};
  float cAcc[4][3] = {};

  __syncthreads();   // prologue staging complete

  for (int jt = 0; jt < 4; ++jt) {
    const int jb = jt * 128;

    // ---- L1: act1 = silu(G + Base + n2*We1n) -> bufA ; stash mask ----
    #pragma unroll
    for (int jj = 0; jj < 2; ++jj) {
      const int jloc = jj * 64 + wid * 16 + l15;
      const int j = jb + jloc;
      const size_t xo = ((size_t)(b * NN + j)) * 3;
      const float dx = x[xo + 0] - xi0;
      const float dy = x[xo + 1] - xi1;
      const float dz = x[xo + 2] - xi2;
      const float n2 = dx * dx + dy * dy + dz * dz;
      if (lg == 0) sMaskL[jloc] = mask[mrow + j];
      #pragma unroll
      for (int kk = 0; kk < 4; ++kk) {
        const int kb = lg * 16 + kk * 4;
        const float4 g4 = *(const float4*)&G[((size_t)(b * NN + j)) * 64 + kb];
        const float4 bs = *(const float4*)&sBase[kb];
        const float4 wn = *(const float4*)&sW1n[kb];
        const float v0 = silu_f(g4.x + bs.x + n2 * wn.x);
        const float v1 = silu_f(g4.y + bs.y + n2 * wn.y);
        const float v2 = silu_f(g4.z + bs.z + n2 * wn.z);
        const float v3 = silu_f(g4.w + bs.w + n2 * wn.w);
        pack_store4(sAct, AIDX(jloc, kb), v0, v1, v2, v3);
      }
    }
    __syncthreads();   // B: bufA + sMaskL ready

    // ---- L2: bufA -> bufB ; h_e accum ----
    {
      const f32x4 bias = *(const f32x4*)&sB2[mb + lg * 4];
      #pragma unroll
      for (int nf = 0; nf < 8; ++nf) {
        const int jn = nf * 16 + l15;
        f32x4 acc = bias;
        #pragma unroll
        for (int ks = 0; ks < 2; ++ks) {
          const half8v bh = *(const half8v*)&sAct[AIDX(jn, ks * 32 + lg * 8)];
          acc = __builtin_amdgcn_mfma_f32_16x16x32_f16(w2F[ks], bh, acc, 0, 0, 0);
        }
        const float m = sMaskL[jn];
        float v[4];
        #pragma unroll
        for (int r = 0; r < 4; ++r) { v[r] = silu_f(acc[r]); heAcc[r] = fmaf(v[r], m, heAcc[r]); }
        pack_store4(sAct, 8192 + AIDX(jn, mb + lg * 4), v[0], v[1], v[2], v[3]);
      }
    }
    __syncthreads();   // C: bufB ready (all bufA reads done)

    // ---- C1: bufB -> bufA ----
    {
      const f32x4 bias = *(const f32x4*)&sB3[mb + lg * 4];
      #pragma unroll
      for (int nf = 0; nf < 8; ++nf) {
        const int jn = nf * 16 + l15;
        f32x4 acc = bias;
        #pragma unroll
        for (int ks = 0; ks < 2; ++ks) {
          const half8v bh = *(const half8v*)&sAct[8192 + AIDX(jn, ks * 32 + lg * 8)];
          acc = __builtin_amdgcn_mfma_f32_16x16x32_f16(w3F[ks], bh, acc, 0, 0, 0);
        }
        float v[4];
        #pragma unroll
        for (int r = 0; r < 4; ++r) v[r] = silu_f(acc[r]);
        pack_store4(sAct, AIDX(jn, mb + lg * 4), v[0], v[1], v[2], v[3]);
      }
    }
    __syncthreads();   // D: bufA(act3) ready

    // ---- C2: bufA ; vec*mask recomputed IN-PHASE (no cross-barrier regs) ----
    {
      const f32x4 bias = *(const f32x4*)&sB4[m2 * 16 + lg * 4];
      #pragma unroll
      for (int jj = 0; jj < 4; ++jj) {
        const int jloc = jj * 32 + jh + l15;   // 0..127, all 8 j-blocks over 4 waves
        const int j = jb + jloc;
        const size_t xo = ((size_t)(b * NN + j)) * 3;
        const float dx = x[xo + 0] - xi0;
        const float dy = x[xo + 1] - xi1;
        const float dz = x[xo + 2] - xi2;
        const float n2 = dx * dx + dy * dy + dz * dz;
        const float inv = __builtin_amdgcn_rcpf(n2 * n2 + 1e-10f);
        const float m = mask[mrow + j];
        const float vm0 = dx * inv * m, vm1 = dy * inv * m, vm2 = dz * inv * m;
        const half8v bh0 = *(const half8v*)&sAct[AIDX(jloc, lg * 8)];
        const half8v bh1 = *(const half8v*)&sAct[AIDX(jloc, 32 + lg * 8)];
        f32x4 acc = bias;
        acc = __builtin_amdgcn_mfma_f32_16x16x32_f16(w4F[0], bh0, acc, 0, 0, 0);
        acc = __builtin_amdgcn_mfma_f32_16x16x32_f16(w4F[1], bh1, acc, 0, 0, 0);
        #pragma unroll
        for (int r = 0; r < 4; ++r) {
          cAcc[r][0] = fmaf(acc[r], vm0, cAcc[r][0]);
          cAcc[r][1] = fmaf(acc[r], vm1, cAcc[r][1]);
          cAcc[r][2] = fmaf(acc[r], vm2, cAcc[r][2]);
        }
      }
    }
    __syncthreads();   // E: C2 reads of bufA done (next L1 overwrites bufA)
  }

  // -------- reductions --------
  #pragma unroll
  for (int r = 0; r < 4; ++r) {
    float s = heAcc[r];
    s += __shfl_xor(s, 1); s += __shfl_xor(s, 2); s += __shfl_xor(s, 4); s += __shfl_xor(s, 8);
    if (l15 == 0) sHe[mb + lg * 4 + r] = s;
  }
  #pragma unroll
  for (int r = 0; r < 4; ++r)
    #pragma unroll
    for (int d = 0; d < 3; ++d) {
      float s = cAcc[r][d];
      s += __shfl_xor(s, 1); s += __shfl_xor(s, 2); s += __shfl_xor(s, 4); s += __shfl_xor(s, 8);
      if (l15 == 0) sCombP[wid][(lg * 4 + r) * 3 + d] = s;
    }
  __syncthreads();
  if (tid < 32) {
    const int c = tid, cm2 = c >> 4, cl = c & 15;
    const float s0 = sCombP[cm2][cl * 3 + 0] + sCombP[cm2 + 2][cl * 3 + 0];
    const float s1 = sCombP[cm2][cl * 3 + 1] + sCombP[cm2 + 2][cl * 3 + 1];
    const float s2 = sCombP[cm2][cl * 3 + 2] + sCombP[cm2 + 2][cl * 3 + 2];
    sCN[c] = s0 * s0 + s1 * s1 + s2 * s2;
  }
  __syncthreads();

  // -------- epilogue MLPs (fp32, tiny) --------
  if (tid < 64) {
    float s = bp1[tid];
    #pragma unroll 8
    for (int c = 0; c < 32; ++c) s = fmaf(sCN[c], Wp1[c * 64 + tid], s);
    sTmp[tid] = silu_f(s);
  }
  __syncthreads();
  if (tid < 64) {
    float s = bp2[tid];
    #pragma unroll 16
    for (int k = 0; k < 64; ++k) s = fmaf(sTmp[k], Wp2[k * 64 + tid], s);
    sHcomb[tid] = s;
  }
  __syncthreads();
  if (tid < 64) {
    float s = bn1[tid];
    #pragma unroll 16
    for (int m = 0; m < 64; ++m) s = fmaf(sHi[m],    Wn1[m * 64 + tid],         s);
    #pragma unroll 16
    for (int m = 0; m < 64; ++m) s = fmaf(sHe[m],    Wn1[(64 + m) * 64 + tid],  s);
    #pragma unroll 16
    for (int m = 0; m < 64; ++m) s = fmaf(sHcomb[m], Wn1[(128 + m) * 64 + tid], s);
    sTmp[tid] = silu_f(s);
  }
  __syncthreads();
  if (tid < 64) {
    float s = bn2[tid];
    #pragma unroll 16
    for (int k = 0; k < 64; ++k) s = fmaf(sTmp[k], Wn2[k * 64 + tid], s);
    out[((size_t)(b * NN + i)) * 64 + tid] = sHi[tid] + s;
  } else if (tid < 67) {
    const int d = tid - 64;
    out[(size_t)BB * NN * FF + ((size_t)(b * NN + i)) * 3 + d] = x[((size_t)(b * NN + i)) * 3 + d];
  }
}

extern "C" void kernel_launch(void* const* d_in, const int* in_sizes, int n_in,
                              void* d_out, int out_size, void* d_ws, size_t ws_size,
                              hipStream_t stream) {
  const float* h    = (const float*)d_in[0];
  const float* x    = (const float*)d_in[1];
  const float* mask = (const float*)d_in[2];
  const float* We1  = (const float*)d_in[3];
  const float* be1  = (const float*)d_in[4];
  const float* We2  = (const float*)d_in[5];
  const float* be2  = (const float*)d_in[6];
  const float* Wc1  = (const float*)d_in[7];
  const float* bc1  = (const float*)d_in[8];
  const float* Wc2  = (const float*)d_in[9];
  const float* bc2  = (const float*)d_in[10];
  const float* Wp1  = (const float*)d_in[11];
  const float* bp1  = (const float*)d_in[12];
  const float* Wp2  = (const float*)d_in[13];
  const float* bp2  = (const float*)d_in[14];
  const float* Wn1  = (const float*)d_in[15];
  const float* bn1  = (const float*)d_in[16];
  const float* Wn2  = (const float*)d_in[17];
  const float* bn2  = (const float*)d_in[18];
  float* out = (float*)d_out;

  float* G    = (float*)d_ws;                       // 2048*64 f32
  float* Base = G + 2048 * 64;                      // 2048*64 f32
  unsigned short* w2f = (unsigned short*)(Base + 2048 * 64);
  unsigned short* w3f = w2f + 4096;
  unsigned short* w4f = w3f + 4096;

  hipLaunchKernelGGL(sake_prep, dim3(65), dim3(256), 0, stream,
                     h, We1, be1, We2, Wc1, Wc2, G, Base, w2f, w3f, w4f);
  hipLaunchKernelGGL(sake_mfma, dim3(BB * NN), dim3(256), 0, stream,
                     h, x, mask, We1, be2, bc1, bc2,
                     Wp1, bp1, Wp2, bp2, Wn1, bn1, Wn2, bn2,
                     G, Base, w2f, w3f, w4f, out);
}